// Round 5
// baseline (103.041 us; speedup 1.0000x reference)
//
#include <hip/hip_runtime.h>

// NegativeSelection: score[i] = max(min_j ||x_i - s_j|| - 0.1, 0)
// N=16384, M=8192, D=128, fp32 in/out.
//
// d2 = a2 + b2 - 2*dot. dot via fp16 MFMA (32x32x16), A pre-negated so
// acc = C_init(b2/2) + (-x)·s = b2/2 - dot; min over j tracked per row.
// final: d2 = a2 + 2*min, score = max(sqrt(max(d2,0)) - 0.1, 0).
//
// This revision attacks the measured LDS-read-BW bound (MfmaUtil 31% ==
// 512cy MFMA vs ~1800cy LDS at 4x B-frag duplication):
//  - waves are now 128 rows x 32 cols (2 row-groups x 4 col-groups):
//    each B fragment read by 2 waves instead of 4 -> LDS reads halved.
//  - A frags = 128 VGPR/wave; to fit 256 VGPR: one acc per rt processed
//    in 2 rt-pair passes (B frags held in regs across passes), and the
//    running min kept as PACKED F16 (cvt_pkrtz + v_pk_min_f16, 32 regs).
//  - ring-3 LDS staging with counted s_waitcnt vmcnt(4) kept verbatim.
//
// ws: Aws fp16 [N*128] (4 MB, [k8][row][8], NEGATED), Bws fp16 [M*128] (2 MB),
//     b2h f32 [M], Pmin f32 [N*16], a2 f32 [N]  -> ~7.3 MB.

using half_t = _Float16;
typedef _Float16 half8 __attribute__((ext_vector_type(8)));
typedef _Float16 half2v __attribute__((ext_vector_type(2)));
typedef float floatx16 __attribute__((ext_vector_type(16)));

#define TILE_ELEMS (128 * 128)   // 32 KB fp16

__device__ __forceinline__ void async_load16(const void* g, void* l) {
    __builtin_amdgcn_global_load_lds(
        (const __attribute__((address_space(1))) void*)g,
        (__attribute__((address_space(3))) void*)l, 16, 0, 0);
}

// 512 threads stage one 32 KB tile: 4 chunks of 16 B per thread, linear.
__device__ __forceinline__ void stage_tile(const half_t* __restrict__ Bt,
                                           half_t* __restrict__ dst, int tid) {
    #pragma unroll
    for (int j = 0; j < 4; ++j) {
        int chunk = j * 512 + tid;
        async_load16(Bt + (size_t)chunk * 8, dst + (size_t)chunk * 8);
    }
}

__device__ __forceinline__ half2v h2min(half2v a, half2v b) {
    return __builtin_elementwise_min(a, b);   // v_pk_min_f16
}

__device__ __forceinline__ half2v pkrtz(float lo, float hi) {
    auto t = __builtin_amdgcn_cvt_pkrtz(lo, hi);
    return __builtin_bit_cast(half2v, t);
}

// One block per 128x128 tile. fp32 -> fp16 tiled layout [k8][row][8]
// (chunk c = k8*128+row stored at element c*8). A negated.
// B tiles: b2h = 0.5*sum(row^2). A tiles: a2 = sum(row^2).
__global__ __launch_bounds__(256) void prep_kernel(
    const float* __restrict__ x, const float* __restrict__ self,
    half_t* __restrict__ Aws, half_t* __restrict__ Bws,
    float* __restrict__ b2h, float* __restrict__ a2, int Atiles)
{
    __shared__ float part[256];
    int tile = blockIdx.x;
    int tid  = threadIdx.x;
    bool isB = tile >= Atiles;
    int bt   = tile - Atiles;
    const float* src = isB ? (self + (size_t)bt * TILE_ELEMS)
                           : (x    + (size_t)tile * TILE_ELEMS);
    half_t* dst = isB ? (Bws + (size_t)bt * TILE_ELEMS)
                      : (Aws + (size_t)tile * TILE_ELEMS);
    float sgn = isB ? 1.f : -1.f;

    int rowt = tid & 127;
    int k8b  = tid >> 7;
    float ss = 0.f;
    #pragma unroll
    for (int i = 0; i < 8; ++i) {
        int k8 = i * 2 + k8b;
        const float4* p = (const float4*)(src + rowt * 128 + k8 * 8);
        float4 f0 = p[0];
        float4 f1 = p[1];
        half8 h;
        h[0] = (half_t)(sgn * f0.x); h[1] = (half_t)(sgn * f0.y);
        h[2] = (half_t)(sgn * f0.z); h[3] = (half_t)(sgn * f0.w);
        h[4] = (half_t)(sgn * f1.x); h[5] = (half_t)(sgn * f1.y);
        h[6] = (half_t)(sgn * f1.z); h[7] = (half_t)(sgn * f1.w);
        *(half8*)(dst + (size_t)(i * 256 + tid) * 8) = h;
        ss += f0.x*f0.x + f0.y*f0.y + f0.z*f0.z + f0.w*f0.w;
        ss += f1.x*f1.x + f1.y*f1.y + f1.z*f1.z + f1.w*f1.w;
    }
    part[tid] = ss;
    __syncthreads();
    if (tid < 128) {
        float tot = part[tid] + part[tid + 128];
        if (isB) b2h[bt * 128 + tid] = 0.5f * tot;
        else     a2[tile * 128 + tid] = tot;
    }
}

// One pipeline iteration. VN = vmcnt allowance at the top (4 mid-loop:
// tile t's 4 loads retired, tile t+1's may remain in flight; 0 last iter).
template<int VN>
__device__ __forceinline__ void gemm_iter(
    int t, int iters, int tid, int wc, int ln31, int lh,
    const half_t* __restrict__ Bbase, half_t (*ring)[TILE_ELEMS],
    const float* __restrict__ b2sh,
    const half8 (&areg)[4][8], half2v (&minacc)[4][8])
{
    __builtin_amdgcn_sched_barrier(0);
    if constexpr (VN == 4) asm volatile("s_waitcnt vmcnt(4)" ::: "memory");
    else                   asm volatile("s_waitcnt vmcnt(0)" ::: "memory");
    asm volatile("s_waitcnt lgkmcnt(0)" ::: "memory");
    __builtin_amdgcn_s_barrier();   // tile t readable; ring[(t+2)%3] free
    __builtin_amdgcn_sched_barrier(0);

    // Stage tile t+2 into the buffer last read at iter t-1.
    if (t + 2 < iters)
        stage_tile(Bbase + (size_t)(t + 2) * TILE_ELEMS, &ring[(t + 2) % 3][0], tid);

    const half_t* Bs = &ring[t % 3][0];
    float b2v = b2sh[t * 128 + wc * 32 + ln31];

    // B frags for this wave's 32-col block, held across both rt passes.
    half8 bf[8];
    #pragma unroll
    for (int ki = 0; ki < 8; ++ki)
        bf[ki] = *(const half8*)(Bs + (size_t)((ki * 2 + lh) * 128 + wc * 32 + ln31) * 8);

    floatx16 c0;
    #pragma unroll
    for (int r = 0; r < 16; ++r) c0[r] = b2v;

    #pragma unroll
    for (int rp = 0; rp < 2; ++rp) {
        floatx16 a0 = __builtin_amdgcn_mfma_f32_32x32x16_f16(areg[rp * 2][0],     bf[0], c0, 0, 0, 0);
        floatx16 a1 = __builtin_amdgcn_mfma_f32_32x32x16_f16(areg[rp * 2 + 1][0], bf[0], c0, 0, 0, 0);
        #pragma unroll
        for (int ki = 1; ki < 8; ++ki) {
            a0 = __builtin_amdgcn_mfma_f32_32x32x16_f16(areg[rp * 2][ki],     bf[ki], a0, 0, 0, 0);
            a1 = __builtin_amdgcn_mfma_f32_32x32x16_f16(areg[rp * 2 + 1][ki], bf[ki], a1, 0, 0, 0);
        }
        // acc = b2/2 - dot; fold into packed-f16 running min.
        #pragma unroll
        for (int i = 0; i < 8; ++i) {
            minacc[rp * 2][i]     = h2min(minacc[rp * 2][i],     pkrtz(a0[2 * i], a0[2 * i + 1]));
            minacc[rp * 2 + 1][i] = h2min(minacc[rp * 2 + 1][i], pkrtz(a1[2 * i], a1[2 * i + 1]));
        }
    }
}

// Grid: (N/256, 4 M-slices), 512 threads = 8 waves (2 row-groups x 4 col-
// groups). Wave (wr,wc): rows wr*128..+128, cols wc*32..+32 of each tile.
__global__ __launch_bounds__(512, 2) void min_gemm_kernel(
    const half_t* __restrict__ Aws, const half_t* __restrict__ Bws,
    const float* __restrict__ b2h, float* __restrict__ Pmin, int Mslice)
{
    __shared__ half_t ring[3][TILE_ELEMS];   // 96 KB
    __shared__ float  b2sh[2048];            // 8 KB (Mslice = 2048)

    int tid  = threadIdx.x;
    int lane = tid & 63;
    int wid  = tid >> 6;
    int wr   = wid >> 2;          // 0..1 : 128-row group
    int wc   = wid & 3;           // 0..3 : 32-col group
    int ln31 = lane & 31, lh = lane >> 5;

    // A fragments: rows (bx*2+wr)*128 + rt*32 + ln31, full K, in regs (128 VGPR).
    const half_t* Atile = Aws + (size_t)(blockIdx.x * 2 + wr) * TILE_ELEMS;
    half8 areg[4][8];
    #pragma unroll
    for (int rt = 0; rt < 4; ++rt)
        #pragma unroll
        for (int ki = 0; ki < 8; ++ki)
            areg[rt][ki] = *(const half8*)(
                Atile + (size_t)((ki * 2 + lh) * 128 + rt * 32 + ln31) * 8);

    // b2 slice -> LDS (keeps main-loop vmcnt domain staging-only).
    int s = blockIdx.y;
    for (int j = tid; j < Mslice; j += 512)
        b2sh[j] = b2h[s * Mslice + j];

    half2v minacc[4][8];
    const half_t HMAX = (half_t)65504.f;
    #pragma unroll
    for (int rt = 0; rt < 4; ++rt)
        #pragma unroll
        for (int i = 0; i < 8; ++i) { minacc[rt][i][0] = HMAX; minacc[rt][i][1] = HMAX; }

    int iters = Mslice >> 7;   // 16
    const half_t* Bbase = Bws + (size_t)s * iters * TILE_ELEMS;

    __syncthreads();   // b2sh visible; vmcnt/lgkm fully drained (once)

    // Prologue: 2-deep prefetch.
    stage_tile(Bbase,              &ring[0][0], tid);
    stage_tile(Bbase + TILE_ELEMS, &ring[1][0], tid);

    for (int t = 0; t < iters - 1; ++t)
        gemm_iter<4>(t, iters, tid, wc, ln31, lh, Bbase, ring, b2sh, areg, minacc);
    gemm_iter<0>(iters - 1, iters, tid, wc, ln31, lh, Bbase, ring, b2sh, areg, minacc);

    // Packed cross-lane min over the 32 column-lanes, then unpack + write.
    // C/D row of element r: (r&3) + 8*(r>>2) + 4*lh; packed pair = r=2i,2i+1.
    #pragma unroll
    for (int rt = 0; rt < 4; ++rt)
        #pragma unroll
        for (int i = 0; i < 8; ++i) {
            int m = __builtin_bit_cast(int, minacc[rt][i]);
            #pragma unroll
            for (int x = 1; x < 32; x <<= 1) {
                int o = __shfl_xor(m, x, 64);
                m = __builtin_bit_cast(int,
                        h2min(__builtin_bit_cast(half2v, m),
                              __builtin_bit_cast(half2v, o)));
            }
            if (ln31 == 0) {
                half2v mv = __builtin_bit_cast(half2v, m);
                int r0 = 2 * i, r1 = 2 * i + 1;
                int rowb = blockIdx.x * 256 + wr * 128 + rt * 32 + 4 * lh;
                int row0 = rowb + (r0 & 3) + 8 * (r0 >> 2);
                int row1 = rowb + (r1 & 3) + 8 * (r1 >> 2);
                Pmin[(size_t)row0 * 16 + s * 4 + wc] = (float)mv[0];
                Pmin[(size_t)row1 * 16 + s * 4 + wc] = (float)mv[1];
            }
        }
}

// One thread per row: min of 16 partials, d2 = a2 + 2*min, sqrt/shift/clamp.
__global__ __launch_bounds__(256) void final_kernel(
    const float* __restrict__ a2, const float* __restrict__ Pmin,
    float* __restrict__ out)
{
    int row = blockIdx.x * 256 + threadIdx.x;
    const float4* pp = (const float4*)(Pmin + (size_t)row * 16);
    float4 p0 = pp[0];
    float4 p1 = pp[1];
    float4 p2 = pp[2];
    float4 p3 = pp[3];
    float q0 = fminf(fminf(p0.x, p0.y), fminf(p0.z, p0.w));
    float q1 = fminf(fminf(p1.x, p1.y), fminf(p1.z, p1.w));
    float q2 = fminf(fminf(p2.x, p2.y), fminf(p2.z, p2.w));
    float q3 = fminf(fminf(p3.x, p3.y), fminf(p3.z, p3.w));
    float p  = fminf(fminf(q0, q1), fminf(q2, q3));
    float d2 = a2[row] + 2.f * p;
    float d  = sqrtf(fmaxf(d2, 0.f));
    out[row] = fmaxf(d - 0.1f, 0.f);
}

extern "C" void kernel_launch(void* const* d_in, const int* in_sizes, int n_in,
                              void* d_out, int out_size, void* d_ws, size_t ws_size,
                              hipStream_t stream)
{
    const float* x    = (const float*)d_in[0];
    const float* self = (const float*)d_in[1];
    float* out        = (float*)d_out;

    int N = in_sizes[0] / 128;   // 16384
    int M = in_sizes[1] / 128;   // 8192
    int Atiles = N / 128;        // 128
    int Btiles = M / 128;        // 64

    char* w      = (char*)d_ws;
    half_t* Aws  = (half_t*)w;
    half_t* Bws  = Aws + (size_t)N * 128;
    float*  b2h  = (float*)(w + (size_t)(N + M) * 128 * 2);
    float*  Pmin = b2h + M;
    float*  a2   = Pmin + (size_t)N * 16;
    // ws: 4 MB + 2 MB + 32 KB + 1 MB + 64 KB ≈ 7.3 MB

    prep_kernel<<<Atiles + Btiles, 256, 0, stream>>>(x, self, Aws, Bws, b2h, a2, Atiles);

    int Mslice = M / 4;          // 2048 -> 16 tile-iterations
    dim3 grid(N / 256, 4);       // 256 blocks = exactly 1/CU, 8 waves each
    min_gemm_kernel<<<grid, 512, 0, stream>>>(Aws, Bws, b2h, Pmin, Mslice);

    final_kernel<<<N / 256, 256, 0, stream>>>(a2, Pmin, out);
}